// Round 3
// baseline (1529.368 us; speedup 1.0000x reference)
//
#include <hip/hip_runtime.h>
#include <math.h>

#define T_TOK 16384
#define HID   1024
#define FFN   4096
#define NEXP  8

typedef __bf16 bf16x8 __attribute__((ext_vector_type(8)));
typedef float  f32x4  __attribute__((ext_vector_type(4)));
typedef const __attribute__((address_space(1))) void* gptr_t;
typedef __attribute__((address_space(3))) void* lptr_t;
typedef unsigned short ushort_t;

__device__ __forceinline__ unsigned short f2bf(float f){
  unsigned u = __float_as_uint(f);
  u += 0x7fffu + ((u >> 16) & 1u);
  return (unsigned short)(u >> 16);
}

__device__ __forceinline__ float gelu_f(float x){
  // jax.nn.gelu default = tanh approximation
  float u = 0.7978845608028654f * x * (1.0f + 0.044715f * x * x);
  return 0.5f * x * (1.0f + tanhf(u));
}

// ---------------- f32 -> bf16 bulk convert (8 elems/thread) ----------------
__global__ void cvt_bf16_kernel(const float* __restrict__ in, ushort_t* __restrict__ out, int n8){
  int i = blockIdx.x * 256 + threadIdx.x;
  if (i >= n8) return;
  const float4* p = (const float4*)in + (size_t)i * 2;
  float4 a = p[0], b = p[1];
  ushort_t r[8] = {f2bf(a.x), f2bf(a.y), f2bf(a.z), f2bf(a.w),
                   f2bf(b.x), f2bf(b.y), f2bf(b.z), f2bf(b.w)};
  ((uint4*)out)[i] = *(const uint4*)r;
}

// ---------------- tiled transpose + convert: out[C][R] = bf16(in[R][C]) ----------------
__global__ void transpose_cvt_kernel(const float* __restrict__ in, ushort_t* __restrict__ out,
                                     int R, int C, long mstride){
  __shared__ float tl[64][65];
  const float* src = in + (long)blockIdx.z * mstride;
  ushort_t*    dst = out + (long)blockIdx.z * mstride;
  int r0 = blockIdx.y * 64, c0 = blockIdx.x * 64;
  int tid = threadIdx.x;
  #pragma unroll
  for (int rep = 0; rep < 16; ++rep){
    int lin = rep * 256 + tid; int rr = lin >> 6, cc = lin & 63;
    tl[rr][cc] = src[(long)(r0 + rr) * C + c0 + cc];
  }
  __syncthreads();
  #pragma unroll
  for (int rep = 0; rep < 16; ++rep){
    int lin = rep * 256 + tid; int rr = lin >> 6, cc = lin & 63;
    dst[(long)(c0 + rr) * R + r0 + cc] = f2bf(tl[cc][rr]);
  }
}

// ---------------- router prep: Wr = attn_w @ router_w (f64), br = attn_b @ router_w ----------------
__global__ void router_prep_kernel(const float* __restrict__ aw, const float* __restrict__ rw,
                                   const float* __restrict__ ab,
                                   double* __restrict__ Wr, double* __restrict__ br){
  int idx = blockIdx.x * 256 + threadIdx.x;
  if (idx < HID * NEXP){
    int h = idx >> 3, e = idx & 7;
    double acc = 0.0;
    for (int k = 0; k < HID; ++k) acc = fma((double)aw[h * HID + k], (double)rw[k * NEXP + e], acc);
    Wr[idx] = acc;
  }
  if (blockIdx.x == 0 && threadIdx.x < NEXP){
    double s = 0.0;
    for (int k = 0; k < HID; ++k) s = fma((double)ab[k], (double)rw[k * NEXP + threadIdx.x], s);
    br[threadIdx.x] = s;
  }
}

// ---------------- router: f64 logits, softmax, top-2, build per-expert lists ----------------
__global__ void router_kernel(const float* __restrict__ x, const double* __restrict__ Wr,
                              const double* __restrict__ br,
                              int2* __restrict__ list, int* __restrict__ cnt){
  __shared__ int   pickE[32];
  __shared__ float pickG[32];
  int tid = threadIdx.x;
  int lt = tid >> 4;       // local token 0..15
  int lane16 = tid & 15;
  int tok = blockIdx.x * 16 + lt;

  double acc[8] = {0,0,0,0,0,0,0,0};
  const float* xr = x + (long)tok * HID;
  for (int h = lane16; h < HID; h += 16){
    double xv = (double)xr[h];
    const double4* w = (const double4*)(Wr + h * 8);
    double4 w0 = w[0], w1v = w[1];
    acc[0] = fma(xv, w0.x, acc[0]);  acc[1] = fma(xv, w0.y, acc[1]);
    acc[2] = fma(xv, w0.z, acc[2]);  acc[3] = fma(xv, w0.w, acc[3]);
    acc[4] = fma(xv, w1v.x, acc[4]); acc[5] = fma(xv, w1v.y, acc[5]);
    acc[6] = fma(xv, w1v.z, acc[6]); acc[7] = fma(xv, w1v.w, acc[7]);
  }
  #pragma unroll
  for (int e = 0; e < 8; ++e){
    #pragma unroll
    for (int off = 8; off; off >>= 1) acc[e] += __shfl_xor(acc[e], off);
  }
  if (lane16 == 0){
    double lg[8];
    double m = -1e300;
    #pragma unroll
    for (int e = 0; e < 8; ++e){ lg[e] = acc[e] + br[e]; m = lg[e] > m ? lg[e] : m; }
    double p[8]; double s = 0.0;
    #pragma unroll
    for (int e = 0; e < 8; ++e){ p[e] = exp(lg[e] - m); s += p[e]; }
    int i0 = 0;
    #pragma unroll
    for (int e = 1; e < 8; ++e) if (lg[e] > lg[i0]) i0 = e;
    int i1 = (i0 == 0) ? 1 : 0;
    #pragma unroll
    for (int e = 0; e < 8; ++e) if (e != i0 && lg[e] > lg[i1]) i1 = e;
    pickE[lt * 2 + 0] = i0; pickG[lt * 2 + 0] = (float)(p[i0] / s);
    pickE[lt * 2 + 1] = i1; pickG[lt * 2 + 1] = (float)(p[i1] / s);
  }
  __syncthreads();
  if (tid < NEXP){
    int e = tid;
    int n = 0;
    for (int i = 0; i < 32; ++i) if (pickE[i] == e) n++;
    if (n){
      int base = atomicAdd(&cnt[e], n);
      int j = 0;
      for (int i = 0; i < 32; ++i) if (pickE[i] == e){
        int token = blockIdx.x * 16 + (i >> 1);
        list[e * T_TOK + base + j] = make_int2(token * 2 + (i & 1), __float_as_int(pickG[i]));
        ++j;
      }
    }
  }
}

// ---------------- GEMM template: C[M,N] = A[M,K] * Bt[N,K]^T ----------------
// MODE 0: A=xb direct rows, epilogue +bias -> bf16 hb
// MODE 1: A=hb gathered by token, epilogue gelu -> bf16 act[tokenk]
// MODE 2: A=act gathered by tokenk, epilogue atomicAdd gate*v -> f32 out[token]

template<int MODE, int KK>
__device__ __forceinline__ void stage_tiles(const ushort_t* __restrict__ A,
                                            const ushort_t* __restrict__ Bte,
                                            const int* rowSrc,
                                            ushort_t* AsB, ushort_t* BsB,
                                            int row0, int n0, int k0, int wid, int lane){
  #pragma unroll
  for (int r = 0; r < 4; ++r){
    int c  = wid * 4 + r;            // chunk 0..15, wave-uniform
    int le = c * 512 + lane * 8;     // element index in 128x64 tile
    int arow = le >> 6;
    int s  = (le >> 3) & 7;
    int koff = k0 + ((s ^ (arow & 7)) << 3);   // pre-swizzled global source (involution)
    long ga = (MODE == 0) ? (long)(row0 + arow) : (long)rowSrc[arow];
    const ushort_t* srcA = A + ga * KK + koff;
    __builtin_amdgcn_global_load_lds((gptr_t)srcA, (lptr_t)(AsB + c * 512), 16, 0, 0);
    const ushort_t* srcB = Bte + (long)(n0 + arow) * KK + koff;
    __builtin_amdgcn_global_load_lds((gptr_t)srcB, (lptr_t)(BsB + c * 512), 16, 0, 0);
  }
}

template<int MODE, int NN, int KK>
__launch_bounds__(256, 2)
__global__ void gemm_kernel(const ushort_t* __restrict__ A, const ushort_t* __restrict__ Bt,
                            const float* __restrict__ bias,
                            const int2* __restrict__ list, const int* __restrict__ cnt,
                            ushort_t* __restrict__ outb, float* __restrict__ outf, int M0){
  __shared__ __attribute__((aligned(16))) ushort_t As[128][64];
  __shared__ __attribute__((aligned(16))) ushort_t Bs[128][64];
  __shared__ int   rowSrc[128];
  __shared__ int   rowDst[128];
  __shared__ float rowGate[128];

  int tid  = threadIdx.x;
  int lane = tid & 63;
  int wid  = tid >> 6;
  int wm = wid >> 1, wn = wid & 1;

  constexpr int NT = NN / 128;
  constexpr int KT = KK / 64;

  int pref[9];
  int total;
  if constexpr (MODE == 0){
    total = (M0 / 128) * NT;
  } else {
    pref[0] = 0;
    #pragma unroll
    for (int e = 0; e < 8; ++e){
      int c = cnt[e];
      pref[e + 1] = pref[e] + ((c + 127) >> 7) * NT;
    }
    total = pref[8];
  }

  for (int task = blockIdx.x; task < total; task += gridDim.x){
    int e = 0, mt, nt, row0, Mrows;
    const ushort_t* Bte;
    if constexpr (MODE == 0){
      mt = task / NT; nt = task - mt * NT; row0 = mt * 128; Mrows = M0; Bte = Bt;
    } else {
      while (task >= pref[e + 1]) ++e;
      int rem = task - pref[e];
      mt = rem / NT; nt = rem - mt * NT; row0 = mt * 128; Mrows = cnt[e];
      Bte = Bt + (size_t)e * NN * KK;
    }
    int n0 = nt * 128;

    if constexpr (MODE != 0){
      if (tid < 128){
        int pos = row0 + tid;
        int cpos = (pos < Mrows) ? pos : (Mrows - 1);
        int2 ent = list[e * T_TOK + cpos];
        int tk = ent.x;
        rowSrc[tid]  = (MODE == 1) ? (tk >> 1) : tk;
        rowDst[tid]  = (pos < Mrows) ? tk : -1;
        rowGate[tid] = __int_as_float(ent.y);
      }
    }
    __syncthreads();

    stage_tiles<MODE, KK>(A, Bte, rowSrc, &As[0][0], &Bs[0][0], row0, n0, 0, wid, lane);

    f32x4 acc[4][4] = {};

    #pragma unroll 1
    for (int kt = 0; kt < KT; ++kt){
      __syncthreads();   // staging for kt complete (drains vmcnt)
      #pragma unroll
      for (int kk = 0; kk < 2; ++kk){
        bf16x8 af[4], bfr[4];
        int ks = kk * 4 + (lane >> 4);
        #pragma unroll
        for (int mi = 0; mi < 4; ++mi){
          int row = wm * 64 + mi * 16 + (lane & 15);
          af[mi] = *reinterpret_cast<const bf16x8*>(&As[row][(ks ^ (row & 7)) << 3]);
        }
        #pragma unroll
        for (int ni = 0; ni < 4; ++ni){
          int col = wn * 64 + ni * 16 + (lane & 15);
          bfr[ni] = *reinterpret_cast<const bf16x8*>(&Bs[col][(ks ^ (col & 7)) << 3]);
        }
        #pragma unroll
        for (int mi = 0; mi < 4; ++mi)
          #pragma unroll
          for (int ni = 0; ni < 4; ++ni)
            acc[mi][ni] = __builtin_amdgcn_mfma_f32_16x16x32_bf16(af[mi], bfr[ni], acc[mi][ni], 0, 0, 0);
      }
      __syncthreads();   // all waves done reading LDS
      if (kt + 1 < KT)
        stage_tiles<MODE, KK>(A, Bte, rowSrc, &As[0][0], &Bs[0][0], row0, n0, (kt + 1) * 64, wid, lane);
    }

    // epilogue: D row = (lane>>4)*4 + r, col = lane&15 within each 16x16 frag
    #pragma unroll
    for (int mi = 0; mi < 4; ++mi){
      #pragma unroll
      for (int r = 0; r < 4; ++r){
        int lrow = wm * 64 + mi * 16 + ((lane >> 4) << 2) + r;
        #pragma unroll
        for (int ni = 0; ni < 4; ++ni){
          int col = n0 + wn * 64 + ni * 16 + (lane & 15);
          float v = acc[mi][ni][r];
          if constexpr (MODE == 0){
            long grow = row0 + lrow;
            outb[grow * NN + col] = f2bf(v + bias[col]);
          } else if constexpr (MODE == 1){
            int d = rowDst[lrow];
            if (d >= 0) outb[(long)d * NN + col] = f2bf(gelu_f(v));
          } else {
            int d = rowDst[lrow];
            if (d >= 0) atomicAdd(&outf[(long)(d >> 1) * NN + col], rowGate[lrow] * v);
          }
        }
      }
    }
    __syncthreads();   // protect row arrays / LDS for next task
  }
}

// ---------------- launcher ----------------
extern "C" void kernel_launch(void* const* d_in, const int* in_sizes, int n_in,
                              void* d_out, int out_size, void* d_ws, size_t ws_size,
                              hipStream_t stream){
  const float* x  = (const float*)d_in[0];
  const float* aw = (const float*)d_in[1];
  const float* ab = (const float*)d_in[2];
  const float* rw = (const float*)d_in[3];
  const float* w1 = (const float*)d_in[4];
  const float* w2 = (const float*)d_in[5];
  float* out = (float*)d_out;

  char* p = (char*)d_ws;
  // act region (268 MB) aliases xb (33.5 MB) + awt (2 MB): both dead before act is written
  ushort_t* act = (ushort_t*)p;
  ushort_t* xb  = (ushort_t*)p;
  ushort_t* awt = (ushort_t*)(p + 33554432);
  size_t off = 268435456;
  ushort_t* w1t = (ushort_t*)(p + off); off += 67108864;
  ushort_t* w2t = (ushort_t*)(p + off); off += 67108864;
  ushort_t* hb  = (ushort_t*)(p + off); off += 33554432;
  double*   Wr  = (double*)(p + off);   off += 65536;
  double*   br  = (double*)(p + off);   off += 256;
  int*      cnt = (int*)(p + off);      off += 256;
  int2*     list= (int2*)(p + off);     off += (size_t)NEXP * T_TOK * 8;

  hipMemsetAsync(d_out, 0, (size_t)out_size * 4, stream);
  hipMemsetAsync(cnt, 0, 32, stream);

  // conversions / transposes
  cvt_bf16_kernel<<<T_TOK * HID / 8 / 256, 256, 0, stream>>>(x, xb, T_TOK * HID / 8);
  transpose_cvt_kernel<<<dim3(HID / 64, HID / 64, 1), 256, 0, stream>>>(aw, awt, HID, HID, (long)HID * HID);
  transpose_cvt_kernel<<<dim3(FFN / 64, HID / 64, NEXP), 256, 0, stream>>>(w1, w1t, HID, FFN, (long)HID * FFN);
  transpose_cvt_kernel<<<dim3(HID / 64, FFN / 64, NEXP), 256, 0, stream>>>(w2, w2t, FFN, HID, (long)HID * FFN);

  // router (f64 logits -> exact ranking)
  router_prep_kernel<<<(HID * NEXP) / 256, 256, 0, stream>>>(aw, rw, ab, Wr, br);
  router_kernel<<<T_TOK / 16, 256, 0, stream>>>(x, Wr, br, list, cnt);

  // h = x @ attn_w + b   (bf16 MFMA)
  gemm_kernel<0, HID, HID><<<1024, 256, 0, stream>>>(xb, awt, ab, nullptr, nullptr, hb, nullptr, T_TOK);
  // act[tokenk] = gelu(h @ w1[e])  (gathered grouped GEMM)
  gemm_kernel<1, FFN, HID><<<4096, 256, 0, stream>>>(hb, w1t, nullptr, list, cnt, act, nullptr, 0);
  // out[token] += gate * (act @ w2[e])
  gemm_kernel<2, HID, FFN><<<2048, 256, 0, stream>>>(act, w2t, nullptr, list, cnt, nullptr, out, 0);
}